// Round 2
// baseline (227.074 us; speedup 1.0000x reference)
//
#include <hip/hip_runtime.h>
#include <math.h>

#define NB 4
#define NL 2048
#define ND 256
#define NPH 64
#define NEH 256
#define PPB 16   // points per block in the MLP kernel

__device__ __forceinline__ float gelu_exact(float x) {
    return 0.5f * x * (1.0f + erff(x * 0.70710678118654752f));
}

// constants evaluated in double at compile time, truncated to float (XLA semantics)
#define DANGER_F ((float)(103.0 / 45.0 / 4.0))
#define REP_F 0.3f
#define MAXD_F 5.0f
#define MIND_F 0.5f
#define OFF_F 0.1f

// ---------------- Kernel A: fused ErrorPredictor MLP ----------------
// 16 points per block, 256 threads. Thread t owns output channel t of h[256].
__global__ __launch_bounds__(256) void mlp_kernel(
    const float* __restrict__ latents, const float* __restrict__ positions,
    const float* __restrict__ pe_w1, const float* __restrict__ pe_b1,
    const float* __restrict__ pe_w2, const float* __restrict__ pe_b2,
    const float* __restrict__ em_w1, const float* __restrict__ em_b1,
    const float* __restrict__ ln_g, const float* __restrict__ ln_b,
    const float* __restrict__ em_w2, const float* __restrict__ em_b2,
    const float* __restrict__ em_w3, const float* __restrict__ em_b3,
    float* __restrict__ errors_out)
{
    const int t = threadIdx.x;
    const int g0 = blockIdx.x * PPB;

    __shared__ float xs[PPB][320];    // concat(latents, pf); rows 0:256 reused for gelu(LN(h))
    __shared__ float pf1[PPB][64];
    __shared__ float h2s[PPB][128];
    __shared__ float red[PPB][4][2];
    __shared__ float stats[PPB][2];   // mu, rstd
    __shared__ float posl[2 * PPB];

    // stage latents (coalesced)
    #pragma unroll
    for (int p = 0; p < PPB; ++p)
        xs[p][t] = latents[(size_t)(g0 + p) * ND + t];
    if (t < PPB) ((float2*)posl)[t] = ((const float2*)positions)[g0 + t];
    __syncthreads();

    // position encoder layer 1: 2 -> 64, gelu. 16 lanes per point, 4 ch each.
    {
        const int p = t >> 4, j0 = t & 15;
        const float px = posl[p * 2], py = posl[p * 2 + 1];
        #pragma unroll
        for (int h = 0; h < 4; ++h) {
            const int j = j0 + 16 * h;
            float v = fmaf(px, pe_w1[j], fmaf(py, pe_w1[64 + j], pe_b1[j]));
            pf1[p][j] = gelu_exact(v);
        }
    }
    __syncthreads();
    // pe layer 2: 64 -> 64
    {
        const int p = t >> 4, j0 = t & 15;
        #pragma unroll
        for (int h = 0; h < 4; ++h) {
            const int j = j0 + 16 * h;
            float acc = pe_b2[j];
            #pragma unroll 4
            for (int k = 0; k < 64; ++k)
                acc = fmaf(pf1[p][k], pe_w2[k * 64 + j], acc);
            xs[p][ND + j] = acc;
        }
    }
    __syncthreads();

    // main matmul: h[p][t] = sum_k xs[p][k] * em_w1[k][t] + b1[t]
    float acc[PPB];
    {
        const float b1 = em_b1[t];
        #pragma unroll
        for (int p = 0; p < PPB; ++p) acc[p] = b1;
    }
    for (int k = 0; k < 320; k += 4) {
        const float w0 = em_w1[(k + 0) * 256 + t];
        const float w1 = em_w1[(k + 1) * 256 + t];
        const float w2 = em_w1[(k + 2) * 256 + t];
        const float w3 = em_w1[(k + 3) * 256 + t];
        #pragma unroll
        for (int p = 0; p < PPB; ++p) {
            const float4 xv = *(const float4*)&xs[p][k];   // ds_read_b128, wave-uniform
            acc[p] = fmaf(xv.x, w0, acc[p]);
            acc[p] = fmaf(xv.y, w1, acc[p]);
            acc[p] = fmaf(xv.z, w2, acc[p]);
            acc[p] = fmaf(xv.w, w3, acc[p]);
        }
    }

    // LayerNorm stats
    const int lane = t & 63, wid = t >> 6;
    #pragma unroll
    for (int p = 0; p < PPB; ++p) {
        float s = acc[p], s2 = acc[p] * acc[p];
        #pragma unroll
        for (int m = 1; m < 64; m <<= 1) {
            s  += __shfl_xor(s, m);
            s2 += __shfl_xor(s2, m);
        }
        if (lane == 0) { red[p][wid][0] = s; red[p][wid][1] = s2; }
    }
    __syncthreads();
    if (t < PPB) {
        float s = 0.f, s2 = 0.f;
        #pragma unroll
        for (int w = 0; w < 4; ++w) { s += red[t][w][0]; s2 += red[t][w][1]; }
        const float mu = s * (1.0f / 256.0f);
        const float var = s2 * (1.0f / 256.0f) - mu * mu;
        stats[t][0] = mu;
        stats[t][1] = 1.0f / sqrtf(var + 1e-5f);
    }
    __syncthreads();
    {
        const float g = ln_g[t], bb = ln_b[t];
        #pragma unroll
        for (int p = 0; p < PPB; ++p) {
            const float hn = fmaf((acc[p] - stats[p][0]) * stats[p][1], g, bb);
            xs[p][t] = gelu_exact(hn);   // reuse xs[:, 0:256]
        }
    }
    __syncthreads();

    // h2 = gelu(hs @ em_w2 + b2): 256 -> 128. thread (j = t&127, half = t>>7) does 8 points.
    {
        const int j = t & 127, ph = t >> 7;
        #pragma unroll
        for (int p = ph * (PPB / 2); p < (ph + 1) * (PPB / 2); ++p) {
            float a2 = em_b2[j];
            for (int k = 0; k < 256; k += 4) {
                const float4 xv = *(const float4*)&xs[p][k];
                a2 = fmaf(xv.x, em_w2[(k + 0) * 128 + j], a2);
                a2 = fmaf(xv.y, em_w2[(k + 1) * 128 + j], a2);
                a2 = fmaf(xv.z, em_w2[(k + 2) * 128 + j], a2);
                a2 = fmaf(xv.w, em_w2[(k + 3) * 128 + j], a2);
            }
            h2s[p][j] = gelu_exact(a2);
        }
    }
    __syncthreads();

    // err = softplus(h2 @ em_w3 + b3). 16 lanes per point.
    {
        const int p = t >> 4, l = t & 15;
        float s = 0.f;
        #pragma unroll
        for (int m = 0; m < 8; ++m)
            s = fmaf(h2s[p][l + 16 * m], em_w3[l + 16 * m], s);
        #pragma unroll
        for (int m = 1; m < 16; m <<= 1) s += __shfl_xor(s, m);
        if (l == 0) {
            const float x = s + em_b3[0];
            errors_out[g0 + p] = fmaxf(x, 0.0f) + log1pf(expf(-fabsf(x)));
        }
    }
}

// ---------------- Kernel B: per-batch min/max normalize ----------------
__global__ __launch_bounds__(256) void norm_kernel(const float* __restrict__ errors,
                                                   float* __restrict__ errn)
{
    const int b = blockIdx.x, t = threadIdx.x;
    const float* e = errors + b * NL;
    float v[8], mn = 1e30f, mx = -1e30f;
    #pragma unroll
    for (int m = 0; m < 8; ++m) {
        v[m] = e[t + 256 * m];
        mn = fminf(mn, v[m]); mx = fmaxf(mx, v[m]);
    }
    #pragma unroll
    for (int m = 1; m < 64; m <<= 1) {
        mn = fminf(mn, __shfl_xor(mn, m));
        mx = fmaxf(mx, __shfl_xor(mx, m));
    }
    __shared__ float rmn[4], rmx[4];
    const int lane = t & 63, wid = t >> 6;
    if (lane == 0) { rmn[wid] = mn; rmx[wid] = mx; }
    __syncthreads();
    mn = fminf(fminf(rmn[0], rmn[1]), fminf(rmn[2], rmn[3]));
    mx = fmaxf(fmaxf(rmx[0], rmx[1]), fmaxf(rmx[2], rmx[3]));
    const float den = mx - mn + 1e-8f;
    #pragma unroll
    for (int m = 0; m < 8; ++m)
        errn[b * NL + t + 256 * m] = (v[m] - mn) / den + OFF_F;
}

// ---------------- Kernel C: pairwise forces (partial over j-chunk) ----------------
// grid = NB * (NL/256) * S blocks; thread owns one i; j-chunk staged in LDS.
// partials layout: [s][b][2][NL] planar for coalesced read-back.
template <int S>
__global__ __launch_bounds__(256) void pair_kernel(
    const float* __restrict__ positions, const float* __restrict__ errn,
    float* __restrict__ partials)
{
    constexpr int JC = NL / S;
    const int t = threadIdx.x;
    int bid = blockIdx.x;
    const int jc = bid % S; bid /= S;
    const int ic = bid & 7;
    const int b  = bid >> 3;
    const int i  = ic * 256 + t;

    const float2 pi = ((const float2*)positions)[b * NL + i];

    __shared__ float pjx[JC], pjy[JC], ej[JC];
    const int j0 = jc * JC;
    for (int m = t; m < JC; m += 256) {
        const float2 pj = ((const float2*)positions)[b * NL + j0 + m];
        pjx[m] = pj.x; pjy[m] = pj.y;
        ej[m]  = errn[b * NL + j0 + m];
    }
    __syncthreads();

    // self-pair (and any exact-coincident pair) contributes exactly 0:
    // direction = delta*invd = 0 when delta==0, and invd is clamped finite.
    float tx = 0.f, ty = 0.f;
    #pragma unroll 4
    for (int m = 0; m < JC; ++m) {
        const float dx = pjx[m] - pi.x;
        const float dy = pjy[m] - pi.y;
        const float r2 = fmaf(dx, dx, dy * dy);
        const bool tiny = (r2 < 1e-12f);           // ref: dist = max(sqrt(r2), 1e-6)
        const float invd = tiny ? 1e6f : rsqrtf(r2);
        const float dist = tiny ? 1e-6f : r2 * invd;
        float w = ej[m] * invd * invd;             // errn_j / dist^2
        const float viol = DANGER_F - dist;
        if (viol > 0.f)                            // rare (~1e-4 of pairs)
            w -= REP_F * (expf(viol / DANGER_F) - 1.0f);
        tx = fmaf(dx * invd, w, tx);
        ty = fmaf(dy * invd, w, ty);
    }
    float* outx = partials + (((size_t)jc * NB + b) * 2 + 0) * NL;
    float* outy = partials + (((size_t)jc * NB + b) * 2 + 1) * NL;
    outx[i] = tx;
    outy[i] = ty;
}

// ---------------- Kernel D: reduce partials, fmean, displacement, outputs ----------------
__global__ __launch_bounds__(256) void final_kernel(
    const float* __restrict__ positions, const float* __restrict__ partials,
    float* __restrict__ out, int S)
{
    const int b = blockIdx.x, t = threadIdx.x;
    float tx[8], ty[8], fm[8];
    float fsum = 0.f;
    #pragma unroll
    for (int m = 0; m < 8; ++m) {
        const int i = t + 256 * m;
        float sx = 0.f, sy = 0.f;
        for (int s = 0; s < S; ++s) {
            sx += partials[(((size_t)s * NB + b) * 2 + 0) * NL + i];
            sy += partials[(((size_t)s * NB + b) * 2 + 1) * NL + i];
        }
        tx[m] = sx; ty[m] = sy;
        fm[m] = sqrtf(fmaf(sx, sx, sy * sy));
        fsum += fm[m];
    }
    #pragma unroll
    for (int m = 1; m < 64; m <<= 1) fsum += __shfl_xor(fsum, m);
    __shared__ float rs[4];
    const int lane = t & 63, wid = t >> 6;
    if (lane == 0) rs[wid] = fsum;
    __syncthreads();
    const float fmean = (rs[0] + rs[1] + rs[2] + rs[3]) * (1.0f / NL);

    float* newpos = out;
    float* disp   = out + 2 * NB * NL;
    #pragma unroll
    for (int m = 0; m < 8; ++m) {
        const int i = t + 256 * m;
        const float fmag = fm[m];
        const float frel = fmag / (fmean + 1e-8f);
        const float dmag = fminf(fmaxf(frel * MAXD_F, MIND_F), MAXD_F);
        const float fdx = tx[m] / (fmag + 1e-8f);
        const float fdy = ty[m] / (fmag + 1e-8f);
        const float dpx = fdx * dmag, dpy = fdy * dmag;
        const float2 pi = ((const float2*)positions)[b * NL + i];
        ((float2*)newpos)[b * NL + i] = make_float2(pi.x + dpx, pi.y + dpy);
        ((float2*)disp)[b * NL + i]   = make_float2(dpx, dpy);
    }
}

extern "C" void kernel_launch(void* const* d_in, const int* in_sizes, int n_in,
                              void* d_out, int out_size, void* d_ws, size_t ws_size,
                              hipStream_t stream)
{
    const float* latents   = (const float*)d_in[0];
    const float* positions = (const float*)d_in[1];
    const float* pe_w1 = (const float*)d_in[2];
    const float* pe_b1 = (const float*)d_in[3];
    const float* pe_w2 = (const float*)d_in[4];
    const float* pe_b2 = (const float*)d_in[5];
    const float* em_w1 = (const float*)d_in[6];
    const float* em_b1 = (const float*)d_in[7];
    const float* ln_g  = (const float*)d_in[8];
    const float* ln_b  = (const float*)d_in[9];
    const float* em_w2 = (const float*)d_in[10];
    const float* em_b2 = (const float*)d_in[11];
    const float* em_w3 = (const float*)d_in[12];
    const float* em_b3 = (const float*)d_in[13];

    float* out = (float*)d_out;
    float* errors = out + 2 * 2 * NB * NL;      // third output section [B,L]

    float* ws = (float*)d_ws;
    float* errn = ws;                            // NB*NL floats
    float* partials = ws + NB * NL;              // S*NB*2*NL floats

    // pick largest j-split that fits the workspace
    int S = 16;
    const size_t avail = ws_size / sizeof(float);
    while (S > 1 && (size_t)NB * NL + (size_t)S * NB * 2 * NL > avail) S >>= 1;

    mlp_kernel<<<NB * NL / PPB, 256, 0, stream>>>(
        latents, positions, pe_w1, pe_b1, pe_w2, pe_b2,
        em_w1, em_b1, ln_g, ln_b, em_w2, em_b2, em_w3, em_b3, errors);

    norm_kernel<<<NB, 256, 0, stream>>>(errors, errn);

    const int grid = NB * (NL / 256) * S;
    switch (S) {
        case 16: pair_kernel<16><<<grid, 256, 0, stream>>>(positions, errn, partials); break;
        case 8:  pair_kernel<8> <<<grid, 256, 0, stream>>>(positions, errn, partials); break;
        case 4:  pair_kernel<4> <<<grid, 256, 0, stream>>>(positions, errn, partials); break;
        case 2:  pair_kernel<2> <<<grid, 256, 0, stream>>>(positions, errn, partials); break;
        default: pair_kernel<1> <<<grid, 256, 0, stream>>>(positions, errn, partials); break;
    }

    final_kernel<<<NB, 256, 0, stream>>>(positions, partials, out, S);
}

// Round 4
// 193.812 us; speedup vs baseline: 1.1716x; 1.1716x over previous
//
#include <hip/hip_runtime.h>
#include <math.h>

#define NB 4
#define NL 2048
#define ND 256
#define PPB 16   // points per block in the MLP kernel

__device__ __forceinline__ float gelu_exact(float x) {
    return 0.5f * x * (1.0f + erff(x * 0.70710678118654752f));
}

// constants evaluated in double at compile time, truncated to float (XLA semantics)
#define DANGER_F ((float)(103.0 / 45.0 / 4.0))
#define DANGER2_SLACK_F ((float)(103.0 / 45.0 / 4.0 * 103.0 / 45.0 / 4.0 * 1.0001))
#define REP_F 0.3f
#define MAXD_F 5.0f
#define MIND_F 0.5f
#define OFF_F 0.1f

// ---------------- Kernel A: fused ErrorPredictor MLP ----------------
// 512 threads, 16 points per block. Wave w owns points {2w, 2w+1}; lane l owns
// 4 output channels (4l..4l+3) in the main matmul -> coalesced dwordx4 weight
// loads, LayerNorm fully in-wave, h2+softplus tail fully in-register.
__global__ __launch_bounds__(512) void mlp_kernel(
    const float* __restrict__ latents, const float* __restrict__ positions,
    const float* __restrict__ pe_w1, const float* __restrict__ pe_b1,
    const float* __restrict__ pe_w2, const float* __restrict__ pe_b2,
    const float* __restrict__ em_w1, const float* __restrict__ em_b1,
    const float* __restrict__ ln_g, const float* __restrict__ ln_b,
    const float* __restrict__ em_w2, const float* __restrict__ em_b2,
    const float* __restrict__ em_w3, const float* __restrict__ em_b3,
    float* __restrict__ errors_out)
{
    const int t  = threadIdx.x;
    const int g0 = blockIdx.x * PPB;
    const int l  = t & 63;
    const int p0 = (t >> 6) * 2;     // this wave's first point

    __shared__ float xs[PPB][320];   // concat(latents, pf); cols 0:256 reused for gelu(LN(h))
    __shared__ float pf1[PPB][64];
    __shared__ float posl[2 * PPB];

    // stage latents as float4 (coalesced b128)
    {
        const float4* src = (const float4*)(latents + (size_t)g0 * ND);
        #pragma unroll
        for (int m = 0; m < 2; ++m) {
            const int q = t + 512 * m;          // float4 id 0..1023
            const float4 v = src[q];
            *(float4*)&xs[q >> 6][(q & 63) * 4] = v;
        }
    }
    if (t < PPB) ((float2*)posl)[t] = ((const float2*)positions)[g0 + t];
    __syncthreads();

    // position encoder layer 1: 2 -> 64, gelu. (p = t>>5, 2 channels each)
    {
        const int p = t >> 5, j0 = t & 31;
        const float px = posl[2 * p], py = posl[2 * p + 1];
        #pragma unroll
        for (int h = 0; h < 2; ++h) {
            const int j = j0 + 32 * h;
            pf1[p][j] = gelu_exact(fmaf(px, pe_w1[j], fmaf(py, pe_w1[64 + j], pe_b1[j])));
        }
    }
    __syncthreads();
    // pe layer 2: 64 -> 64, into xs[:, 256:320]
    {
        const int p = t >> 5, j0 = t & 31;
        #pragma unroll
        for (int h = 0; h < 2; ++h) {
            const int j = j0 + 32 * h;
            float a = pe_b2[j];
            #pragma unroll 4
            for (int k = 0; k < 64; ++k)
                a = fmaf(pf1[p][k], pe_w2[k * 64 + j], a);
            xs[p][ND + j] = a;
        }
    }
    __syncthreads();
    // ---- no further barriers: each wave only touches its own 2 points below ----

    // main matmul: h[p][c] = sum_k xs[p][k] * em_w1[k][c], c = 4l..4l+3
    float4 acc0 = *(const float4*)&em_b1[4 * l];
    float4 acc1 = acc0;
    {
        const float4* __restrict__ W1 = (const float4*)em_w1;   // [k][64 float4]
        #pragma unroll 2
        for (int k = 0; k < 320; k += 4) {
            const float4 xq0 = *(const float4*)&xs[p0][k];
            const float4 xq1 = *(const float4*)&xs[p0 + 1][k];
            const float xa0[4] = {xq0.x, xq0.y, xq0.z, xq0.w};
            const float xa1[4] = {xq1.x, xq1.y, xq1.z, xq1.w};
            #pragma unroll
            for (int u = 0; u < 4; ++u) {
                const float4 w = W1[(size_t)(k + u) * 64 + l];
                acc0.x = fmaf(xa0[u], w.x, acc0.x);
                acc0.y = fmaf(xa0[u], w.y, acc0.y);
                acc0.z = fmaf(xa0[u], w.z, acc0.z);
                acc0.w = fmaf(xa0[u], w.w, acc0.w);
                acc1.x = fmaf(xa1[u], w.x, acc1.x);
                acc1.y = fmaf(xa1[u], w.y, acc1.y);
                acc1.z = fmaf(xa1[u], w.z, acc1.z);
                acc1.w = fmaf(xa1[u], w.w, acc1.w);
            }
        }
    }

    // LayerNorm: all 256 channels of each point live inside this wave
    float s0 = acc0.x + acc0.y + acc0.z + acc0.w;
    float q0 = acc0.x * acc0.x + acc0.y * acc0.y + acc0.z * acc0.z + acc0.w * acc0.w;
    float s1 = acc1.x + acc1.y + acc1.z + acc1.w;
    float q1 = acc1.x * acc1.x + acc1.y * acc1.y + acc1.z * acc1.z + acc1.w * acc1.w;
    #pragma unroll
    for (int m = 1; m < 64; m <<= 1) {
        s0 += __shfl_xor(s0, m); q0 += __shfl_xor(q0, m);
        s1 += __shfl_xor(s1, m); q1 += __shfl_xor(q1, m);
    }
    const float mu0 = s0 * (1.0f / 256.0f);
    const float rs0 = 1.0f / sqrtf(q0 * (1.0f / 256.0f) - mu0 * mu0 + 1e-5f);
    const float mu1 = s1 * (1.0f / 256.0f);
    const float rs1 = 1.0f / sqrtf(q1 * (1.0f / 256.0f) - mu1 * mu1 + 1e-5f);

    {
        const float4 g4 = *(const float4*)&ln_g[4 * l];
        const float4 b4 = *(const float4*)&ln_b[4 * l];
        float4 o0, o1;
        o0.x = gelu_exact(fmaf((acc0.x - mu0) * rs0, g4.x, b4.x));
        o0.y = gelu_exact(fmaf((acc0.y - mu0) * rs0, g4.y, b4.y));
        o0.z = gelu_exact(fmaf((acc0.z - mu0) * rs0, g4.z, b4.z));
        o0.w = gelu_exact(fmaf((acc0.w - mu0) * rs0, g4.w, b4.w));
        o1.x = gelu_exact(fmaf((acc1.x - mu1) * rs1, g4.x, b4.x));
        o1.y = gelu_exact(fmaf((acc1.y - mu1) * rs1, g4.y, b4.y));
        o1.z = gelu_exact(fmaf((acc1.z - mu1) * rs1, g4.z, b4.z));
        o1.w = gelu_exact(fmaf((acc1.w - mu1) * rs1, g4.w, b4.w));
        *(float4*)&xs[p0][4 * l]     = o0;   // own rows; wave-internal ordering suffices
        *(float4*)&xs[p0 + 1][4 * l] = o1;
    }

    // h2 = gelu(hs @ em_w2 + b2): 256 -> 128. lane l owns channels {2l, 2l+1}.
    float2 a0 = *(const float2*)&em_b2[2 * l];
    float2 a1 = a0;
    {
        const float2* __restrict__ W2 = (const float2*)em_w2;   // [k][64 float2]
        #pragma unroll 2
        for (int k = 0; k < 256; k += 4) {
            const float4 xq0 = *(const float4*)&xs[p0][k];
            const float4 xq1 = *(const float4*)&xs[p0 + 1][k];
            const float xa0[4] = {xq0.x, xq0.y, xq0.z, xq0.w};
            const float xa1[4] = {xq1.x, xq1.y, xq1.z, xq1.w};
            #pragma unroll
            for (int u = 0; u < 4; ++u) {
                const float2 w = W2[(size_t)(k + u) * 64 + l];
                a0.x = fmaf(xa0[u], w.x, a0.x);
                a0.y = fmaf(xa0[u], w.y, a0.y);
                a1.x = fmaf(xa1[u], w.x, a1.x);
                a1.y = fmaf(xa1[u], w.y, a1.y);
            }
        }
    }

    // err = softplus(gelu(h2) @ em_w3 + b3), fully in-register
    {
        const float2 w3 = *(const float2*)&em_w3[2 * l];
        float rA = fmaf(gelu_exact(a0.x), w3.x, gelu_exact(a0.y) * w3.y);
        float rB = fmaf(gelu_exact(a1.x), w3.x, gelu_exact(a1.y) * w3.y);
        #pragma unroll
        for (int m = 1; m < 64; m <<= 1) {
            rA += __shfl_xor(rA, m);
            rB += __shfl_xor(rB, m);
        }
        if (l == 0) {
            const float xA = rA + em_b3[0];
            const float xB = rB + em_b3[0];
            errors_out[g0 + p0]     = fmaxf(xA, 0.0f) + log1pf(expf(-fabsf(xA)));
            errors_out[g0 + p0 + 1] = fmaxf(xB, 0.0f) + log1pf(expf(-fabsf(xB)));
        }
    }
}

// ---------------- Kernel B: per-batch min/max normalize ----------------
__global__ __launch_bounds__(256) void norm_kernel(const float* __restrict__ errors,
                                                   float* __restrict__ errn)
{
    const int b = blockIdx.x, t = threadIdx.x;
    const float* e = errors + b * NL;
    float v[8], mn = 1e30f, mx = -1e30f;
    #pragma unroll
    for (int m = 0; m < 8; ++m) {
        v[m] = e[t + 256 * m];
        mn = fminf(mn, v[m]); mx = fmaxf(mx, v[m]);
    }
    #pragma unroll
    for (int m = 1; m < 64; m <<= 1) {
        mn = fminf(mn, __shfl_xor(mn, m));
        mx = fmaxf(mx, __shfl_xor(mx, m));
    }
    __shared__ float rmn[4], rmx[4];
    const int lane = t & 63, wid = t >> 6;
    if (lane == 0) { rmn[wid] = mn; rmx[wid] = mx; }
    __syncthreads();
    mn = fminf(fminf(rmn[0], rmn[1]), fminf(rmn[2], rmn[3]));
    mx = fmaxf(fmaxf(rmx[0], rmx[1]), fmaxf(rmx[2], rmx[3]));
    const float den = mx - mn + 1e-8f;
    #pragma unroll
    for (int m = 0; m < 8; ++m)
        errn[b * NL + t + 256 * m] = (v[m] - mn) / den + OFF_F;
}

// ---------------- Kernel C: pairwise forces (partial over j-chunk) ----------------
// grid = NB * (NL/256) * S blocks; thread owns one i; j-chunk staged in LDS as
// float4(x, y, errn, 0) -> one broadcast ds_read_b128 per iteration.
// partials: float2 per (s, b, i), layout [s][b][NL].
template <int S>
__global__ __launch_bounds__(256) void pair_kernel(
    const float* __restrict__ positions, const float* __restrict__ errn,
    float2* __restrict__ partials)
{
    constexpr int JC = NL / S;
    const int t = threadIdx.x;
    int bid = blockIdx.x;
    const int jc = bid % S; bid /= S;
    const int ic = bid & 7;
    const int b  = bid >> 3;
    const int i  = ic * 256 + t;

    const float2 pi = ((const float2*)positions)[b * NL + i];

    __shared__ float4 pj4[JC];
    const int j0 = jc * JC;
    for (int m = t; m < JC; m += 256) {
        const float2 pj = ((const float2*)positions)[b * NL + j0 + m];
        pj4[m] = make_float4(pj.x, pj.y, errn[b * NL + j0 + m], 0.0f);
    }
    __syncthreads();

    // self/coincident pairs contribute exactly 0 (delta==0 -> direction 0, invd finite)
    float tx = 0.f, ty = 0.f;
    #pragma unroll 4
    for (int m = 0; m < JC; ++m) {
        const float4 v = pj4[m];
        const float dx = v.x - pi.x;
        const float dy = v.y - pi.y;
        const float r2 = fmaf(dx, dx, dy * dy);
        const bool tiny = (r2 < 1e-12f);           // ref: dist = max(sqrt(r2), 1e-6)
        const float invd = tiny ? 1e6f : rsqrtf(r2);
        float w = v.z * invd * invd;               // errn_j / dist^2
        if (r2 < DANGER2_SLACK_F) {                // rare; exact check + sqrtf inside
            const float dist = fmaxf(sqrtf(r2), 1e-6f);
            const float viol = DANGER_F - dist;
            if (viol > 0.f)
                w -= REP_F * (expf(viol / DANGER_F) - 1.0f);
        }
        const float g = w * invd;
        tx = fmaf(dx, g, tx);
        ty = fmaf(dy, g, ty);
    }
    partials[((size_t)jc * NB + b) * NL + i] = make_float2(tx, ty);
}

// ---------------- Kernel D: reduce partials, fmean, displacement, outputs ----------------
template <int S>
__global__ __launch_bounds__(512) void final_kernel(
    const float* __restrict__ positions, const float2* __restrict__ partials,
    float* __restrict__ out)
{
    const int b = blockIdx.x, t = threadIdx.x;
    float tx[4], ty[4], fm[4];
    float fsum = 0.f;
    #pragma unroll
    for (int m = 0; m < 4; ++m) {
        const int i = t + 512 * m;
        float sx = 0.f, sy = 0.f;
        #pragma unroll
        for (int s = 0; s < S; ++s) {
            const float2 v = partials[((size_t)s * NB + b) * NL + i];
            sx += v.x; sy += v.y;
        }
        tx[m] = sx; ty[m] = sy;
        fm[m] = sqrtf(fmaf(sx, sx, sy * sy));
        fsum += fm[m];
    }
    #pragma unroll
    for (int m = 1; m < 64; m <<= 1) fsum += __shfl_xor(fsum, m);
    __shared__ float rs[8];
    const int lane = t & 63, wid = t >> 6;
    if (lane == 0) rs[wid] = fsum;
    __syncthreads();
    float fmean = 0.f;
    #pragma unroll
    for (int w = 0; w < 8; ++w) fmean += rs[w];
    fmean *= (1.0f / NL);

    float* newpos = out;
    float* disp   = out + 2 * NB * NL;
    #pragma unroll
    for (int m = 0; m < 4; ++m) {
        const int i = t + 512 * m;
        const float fmag = fm[m];
        const float frel = fmag / (fmean + 1e-8f);
        const float dmag = fminf(fmaxf(frel * MAXD_F, MIND_F), MAXD_F);
        const float fdx = tx[m] / (fmag + 1e-8f);
        const float fdy = ty[m] / (fmag + 1e-8f);
        const float dpx = fdx * dmag, dpy = fdy * dmag;
        const float2 pi = ((const float2*)positions)[b * NL + i];
        ((float2*)newpos)[b * NL + i] = make_float2(pi.x + dpx, pi.y + dpy);
        ((float2*)disp)[b * NL + i]   = make_float2(dpx, dpy);
    }
}

extern "C" void kernel_launch(void* const* d_in, const int* in_sizes, int n_in,
                              void* d_out, int out_size, void* d_ws, size_t ws_size,
                              hipStream_t stream)
{
    const float* latents   = (const float*)d_in[0];
    const float* positions = (const float*)d_in[1];
    const float* pe_w1 = (const float*)d_in[2];
    const float* pe_b1 = (const float*)d_in[3];
    const float* pe_w2 = (const float*)d_in[4];
    const float* pe_b2 = (const float*)d_in[5];
    const float* em_w1 = (const float*)d_in[6];
    const float* em_b1 = (const float*)d_in[7];
    const float* ln_g  = (const float*)d_in[8];
    const float* ln_b  = (const float*)d_in[9];
    const float* em_w2 = (const float*)d_in[10];
    const float* em_b2 = (const float*)d_in[11];
    const float* em_w3 = (const float*)d_in[12];
    const float* em_b3 = (const float*)d_in[13];

    float* out = (float*)d_out;
    float* errors = out + 2 * 2 * NB * NL;       // third output section [B,L]

    float* ws = (float*)d_ws;
    float* errn = ws;                             // NB*NL floats
    float2* partials = (float2*)(ws + NB * NL);   // S*NB*NL float2

    // pick largest j-split that fits the workspace
    int S = 32;
    const size_t avail = ws_size / sizeof(float);
    while (S > 1 && (size_t)NB * NL + (size_t)S * NB * 2 * NL > avail) S >>= 1;

    mlp_kernel<<<NB * NL / PPB, 512, 0, stream>>>(
        latents, positions, pe_w1, pe_b1, pe_w2, pe_b2,
        em_w1, em_b1, ln_g, ln_b, em_w2, em_b2, em_w3, em_b3, errors);

    norm_kernel<<<NB, 256, 0, stream>>>(errors, errn);

    const int grid = NB * (NL / 256) * S;
    switch (S) {
        case 32: pair_kernel<32><<<grid, 256, 0, stream>>>(positions, errn, partials); break;
        case 16: pair_kernel<16><<<grid, 256, 0, stream>>>(positions, errn, partials); break;
        case 8:  pair_kernel<8> <<<grid, 256, 0, stream>>>(positions, errn, partials); break;
        case 4:  pair_kernel<4> <<<grid, 256, 0, stream>>>(positions, errn, partials); break;
        case 2:  pair_kernel<2> <<<grid, 256, 0, stream>>>(positions, errn, partials); break;
        default: pair_kernel<1> <<<grid, 256, 0, stream>>>(positions, errn, partials); break;
    }

    switch (S) {
        case 32: final_kernel<32><<<NB, 512, 0, stream>>>(positions, partials, out); break;
        case 16: final_kernel<16><<<NB, 512, 0, stream>>>(positions, partials, out); break;
        case 8:  final_kernel<8> <<<NB, 512, 0, stream>>>(positions, partials, out); break;
        case 4:  final_kernel<4> <<<NB, 512, 0, stream>>>(positions, partials, out); break;
        case 2:  final_kernel<2> <<<NB, 512, 0, stream>>>(positions, partials, out); break;
        default: final_kernel<1> <<<NB, 512, 0, stream>>>(positions, partials, out); break;
    }
}

// Round 7
// 163.156 us; speedup vs baseline: 1.3918x; 1.1879x over previous
//
#include <hip/hip_runtime.h>
#include <math.h>

#define NB 4
#define NL 2048
#define ND 256
#define PPB 32   // points per block in the MLP kernel (8 waves x 4 points)

__device__ __forceinline__ float gelu_exact(float x) {
    return 0.5f * x * (1.0f + erff(x * 0.70710678118654752f));
}

// constants evaluated in double at compile time, truncated to float (XLA semantics)
#define DANGER_F ((float)(103.0 / 45.0 / 4.0))
#define DANGER2_SLACK_F ((float)(103.0 / 45.0 / 4.0 * 103.0 / 45.0 / 4.0 * 1.0001))
#define REP_F 0.3f
#define MAXD_F 5.0f
#define MIND_F 0.5f
#define OFF_F 0.1f

// ---------------- Kernel A: fused ErrorPredictor MLP ----------------
// 512 threads, 32 points per block (8 waves share one L1 weight stream).
// Wave w owns points {4w..4w+3}; lane l owns 4 output channels.
// Register double-buffered weight prefetch (wA/wB) hides L1/L2 latency.
// LayerNorm fully in-wave, h2+softplus tail fully in-register.
__global__ __launch_bounds__(512) void mlp_kernel(
    const float* __restrict__ latents, const float* __restrict__ positions,
    const float* __restrict__ pe_w1, const float* __restrict__ pe_b1,
    const float* __restrict__ pe_w2, const float* __restrict__ pe_b2,
    const float* __restrict__ em_w1, const float* __restrict__ em_b1,
    const float* __restrict__ ln_g, const float* __restrict__ ln_b,
    const float* __restrict__ em_w2, const float* __restrict__ em_b2,
    const float* __restrict__ em_w3, const float* __restrict__ em_b3,
    float* __restrict__ errors_out)
{
    const int t  = threadIdx.x;
    const int g0 = blockIdx.x * PPB;
    const int l  = t & 63;
    const int p0 = (t >> 6) * 4;     // this wave's first point (block-local)

    __shared__ float xs[PPB][320];   // concat(latents, pf); cols 0:256 reused for gelu(LN(h))
    __shared__ float pf1[PPB][64];
    __shared__ float posl[2 * PPB];

    // stage latents as float4 (coalesced b128): 32*64 = 2048 float4, 4/thread
    {
        const float4* src = (const float4*)(latents + (size_t)g0 * ND);
        #pragma unroll
        for (int m = 0; m < 4; ++m) {
            const int q = t + 512 * m;
            const float4 v = src[q];
            *(float4*)&xs[q >> 6][(q & 63) * 4] = v;
        }
    }
    if (t < PPB) ((float2*)posl)[t] = ((const float2*)positions)[g0 + t];
    __syncthreads();

    // position encoder layer 1: 2 -> 64, gelu. 16 lanes/point, 4 ch each.
    {
        const int p = t >> 4, j0 = t & 15;
        const float px = posl[2 * p], py = posl[2 * p + 1];
        #pragma unroll
        for (int h = 0; h < 4; ++h) {
            const int j = j0 + 16 * h;
            pf1[p][j] = gelu_exact(fmaf(px, pe_w1[j], fmaf(py, pe_w1[64 + j], pe_b1[j])));
        }
    }
    __syncthreads();
    // pe layer 2: 64 -> 64, into xs[:, 256:320]
    {
        const int p = t >> 4, j0 = t & 15;
        #pragma unroll
        for (int h = 0; h < 4; ++h) {
            const int j = j0 + 16 * h;
            float a = pe_b2[j];
            #pragma unroll 4
            for (int k = 0; k < 64; ++k)
                a = fmaf(pf1[p][k], pe_w2[k * 64 + j], a);
            xs[p][ND + j] = a;
        }
    }
    __syncthreads();
    // ---- no further barriers: each wave only touches its own 4 points below ----

    // main matmul: h[p][c] = sum_k xs[p][k] * em_w1[k][c], c = 4l..4l+3
    float acc[4][4];
    {
        const float4 b1 = *(const float4*)&em_b1[4 * l];
        #pragma unroll
        for (int p = 0; p < 4; ++p) {
            acc[p][0] = b1.x; acc[p][1] = b1.y; acc[p][2] = b1.z; acc[p][3] = b1.w;
        }
    }

#define MM_CHUNK(KK, W)                                                          \
    {                                                                            \
        float xk[4][4];                                                          \
        _Pragma("unroll")                                                        \
        for (int p = 0; p < 4; ++p) {                                            \
            const float4 xq = *(const float4*)&xs[p0 + p][(KK)];                 \
            xk[p][0] = xq.x; xk[p][1] = xq.y; xk[p][2] = xq.z; xk[p][3] = xq.w;  \
        }                                                                        \
        _Pragma("unroll")                                                        \
        for (int u = 0; u < 4; ++u) {                                            \
            _Pragma("unroll")                                                    \
            for (int p = 0; p < 4; ++p) {                                        \
                acc[p][0] = fmaf(xk[p][u], W[u].x, acc[p][0]);                   \
                acc[p][1] = fmaf(xk[p][u], W[u].y, acc[p][1]);                   \
                acc[p][2] = fmaf(xk[p][u], W[u].z, acc[p][2]);                   \
                acc[p][3] = fmaf(xk[p][u], W[u].w, acc[p][3]);                   \
            }                                                                    \
        }                                                                        \
    }

    {
        const float4* __restrict__ W1 = (const float4*)em_w1;   // [k][64 float4]
        float4 wA[4], wB[4];
        #pragma unroll
        for (int u = 0; u < 4; ++u) wA[u] = W1[(size_t)(0 + u) * 64 + l];
        #pragma unroll
        for (int u = 0; u < 4; ++u) wB[u] = W1[(size_t)(4 + u) * 64 + l];
        for (int k = 0; k < 312; k += 8) {
            MM_CHUNK(k, wA);
            #pragma unroll
            for (int u = 0; u < 4; ++u) wA[u] = W1[(size_t)(k + 8 + u) * 64 + l];
            MM_CHUNK(k + 4, wB);
            #pragma unroll
            for (int u = 0; u < 4; ++u) wB[u] = W1[(size_t)(k + 12 + u) * 64 + l];
        }
        MM_CHUNK(312, wA);
        MM_CHUNK(316, wB);
    }
#undef MM_CHUNK

    // LayerNorm: all 256 channels of each point live inside this wave
    float mu[4], rstd[4];
    #pragma unroll
    for (int p = 0; p < 4; ++p) {
        float s = acc[p][0] + acc[p][1] + acc[p][2] + acc[p][3];
        float q = acc[p][0] * acc[p][0] + acc[p][1] * acc[p][1]
                + acc[p][2] * acc[p][2] + acc[p][3] * acc[p][3];
        #pragma unroll
        for (int m = 1; m < 64; m <<= 1) {
            s += __shfl_xor(s, m);
            q += __shfl_xor(q, m);
        }
        mu[p] = s * (1.0f / 256.0f);
        rstd[p] = 1.0f / sqrtf(q * (1.0f / 256.0f) - mu[p] * mu[p] + 1e-5f);
    }

    {
        const float4 g4 = *(const float4*)&ln_g[4 * l];
        const float4 b4 = *(const float4*)&ln_b[4 * l];
        #pragma unroll
        for (int p = 0; p < 4; ++p) {
            float4 o;
            o.x = gelu_exact(fmaf((acc[p][0] - mu[p]) * rstd[p], g4.x, b4.x));
            o.y = gelu_exact(fmaf((acc[p][1] - mu[p]) * rstd[p], g4.y, b4.y));
            o.z = gelu_exact(fmaf((acc[p][2] - mu[p]) * rstd[p], g4.z, b4.z));
            o.w = gelu_exact(fmaf((acc[p][3] - mu[p]) * rstd[p], g4.w, b4.w));
            *(float4*)&xs[p0 + p][4 * l] = o;   // own rows; wave-internal ordering ok
        }
    }

    // h2 = gelu(hs @ em_w2 + b2): 256 -> 128. lane l owns channels {2l, 2l+1}.
    float a2[4][2];
    {
        const float2 b2 = *(const float2*)&em_b2[2 * l];
        #pragma unroll
        for (int p = 0; p < 4; ++p) { a2[p][0] = b2.x; a2[p][1] = b2.y; }
    }

#define H2_CHUNK(KK, W)                                                          \
    {                                                                            \
        float xk[4][4];                                                          \
        _Pragma("unroll")                                                        \
        for (int p = 0; p < 4; ++p) {                                            \
            const float4 xq = *(const float4*)&xs[p0 + p][(KK)];                 \
            xk[p][0] = xq.x; xk[p][1] = xq.y; xk[p][2] = xq.z; xk[p][3] = xq.w;  \
        }                                                                        \
        _Pragma("unroll")                                                        \
        for (int u = 0; u < 4; ++u) {                                            \
            _Pragma("unroll")                                                    \
            for (int p = 0; p < 4; ++p) {                                        \
                a2[p][0] = fmaf(xk[p][u], W[u].x, a2[p][0]);                     \
                a2[p][1] = fmaf(xk[p][u], W[u].y, a2[p][1]);                     \
            }                                                                    \
        }                                                                        \
    }

    {
        const float2* __restrict__ W2 = (const float2*)em_w2;   // [k][64 float2]
        float2 wA[4], wB[4];
        #pragma unroll
        for (int u = 0; u < 4; ++u) wA[u] = W2[(size_t)(0 + u) * 64 + l];
        #pragma unroll
        for (int u = 0; u < 4; ++u) wB[u] = W2[(size_t)(4 + u) * 64 + l];
        for (int k = 0; k < 248; k += 8) {
            H2_CHUNK(k, wA);
            #pragma unroll
            for (int u = 0; u < 4; ++u) wA[u] = W2[(size_t)(k + 8 + u) * 64 + l];
            H2_CHUNK(k + 4, wB);
            #pragma unroll
            for (int u = 0; u < 4; ++u) wB[u] = W2[(size_t)(k + 12 + u) * 64 + l];
        }
        H2_CHUNK(248, wA);
        H2_CHUNK(252, wB);
    }
#undef H2_CHUNK

    // err = softplus(gelu(h2) @ em_w3 + b3), fully in-register
    {
        const float2 w3 = *(const float2*)&em_w3[2 * l];
        float r[4];
        #pragma unroll
        for (int p = 0; p < 4; ++p)
            r[p] = fmaf(gelu_exact(a2[p][0]), w3.x, gelu_exact(a2[p][1]) * w3.y);
        #pragma unroll
        for (int m = 1; m < 64; m <<= 1) {
            #pragma unroll
            for (int p = 0; p < 4; ++p) r[p] += __shfl_xor(r[p], m);
        }
        if (l == 0) {
            #pragma unroll
            for (int p = 0; p < 4; ++p) {
                const float x = r[p] + em_b3[0];
                errors_out[g0 + p0 + p] = fmaxf(x, 0.0f) + log1pf(expf(-fabsf(x)));
            }
        }
    }
}

// ---------------- Kernel B: per-batch min/max + zero the force accumulator ----------------
// mnden[b] = (e_min, e_max - e_min + 1e-8); force[b][:] = 0.
__global__ __launch_bounds__(256) void minmax_kernel(const float* __restrict__ errors,
                                                     float2* __restrict__ mnden,
                                                     float2* __restrict__ force)
{
    const int b = blockIdx.x, t = threadIdx.x;
    const float* e = errors + b * NL;
    float mn = 1e30f, mx = -1e30f;
    #pragma unroll
    for (int m = 0; m < 8; ++m) {
        const float v = e[t + 256 * m];
        mn = fminf(mn, v); mx = fmaxf(mx, v);
    }
    #pragma unroll
    for (int m = 1; m < 64; m <<= 1) {
        mn = fminf(mn, __shfl_xor(mn, m));
        mx = fmaxf(mx, __shfl_xor(mx, m));
    }
    __shared__ float rmn[4], rmx[4];
    const int lane = t & 63, wid = t >> 6;
    if (lane == 0) { rmn[wid] = mn; rmx[wid] = mx; }
    __syncthreads();
    if (t == 0) {
        mn = fminf(fminf(rmn[0], rmn[1]), fminf(rmn[2], rmn[3]));
        mx = fmaxf(fmaxf(rmx[0], rmx[1]), fmaxf(rmx[2], rmx[3]));
        mnden[b] = make_float2(mn, (mx - mn) + 1e-8f);
    }
    // zero this batch's force slice (harness poisons ws with 0xAA)
    #pragma unroll
    for (int m = 0; m < 8; ++m)
        force[b * NL + t + 256 * m] = make_float2(0.0f, 0.0f);
}

// ---------------- Kernel C: pairwise forces, fixed 1024-block grid, atomic accumulate ----
// grid = NB * 8 * 32 (b, ic, jc); thread owns one i; 64-j chunk staged in LDS as
// float4(x, y, errn, 0) with normalization fused in (exact IEEE div like ref).
__global__ __launch_bounds__(256) void pair_kernel(
    const float* __restrict__ positions, const float* __restrict__ errors,
    const float2* __restrict__ mnden, float2* __restrict__ force)
{
    const int t = threadIdx.x;
    int bid = blockIdx.x;
    const int jc = bid & 31; bid >>= 5;
    const int ic = bid & 7;  bid >>= 3;
    const int b  = bid;
    const int i  = ic * 256 + t;

    const float2 pi = ((const float2*)positions)[b * NL + i];

    __shared__ float4 pj4[64];
    if (t < 64) {
        const int j = jc * 64 + t;
        const float2 pj = ((const float2*)positions)[b * NL + j];
        const float2 md = mnden[b];
        pj4[t] = make_float4(pj.x, pj.y, (errors[b * NL + j] - md.x) / md.y + OFF_F, 0.0f);
    }
    __syncthreads();

    // self/coincident pairs contribute exactly 0 (delta==0 -> direction 0, invd finite)
    float tx = 0.f, ty = 0.f;
    #pragma unroll 4
    for (int m = 0; m < 64; ++m) {
        const float4 v = pj4[m];
        const float dx = v.x - pi.x;
        const float dy = v.y - pi.y;
        const float r2 = fmaf(dx, dx, dy * dy);
        const bool tiny = (r2 < 1e-12f);           // ref: dist = max(sqrt(r2), 1e-6)
        const float invd = tiny ? 1e6f : rsqrtf(r2);
        float w = v.z * invd * invd;               // errn_j / dist^2
        if (r2 < DANGER2_SLACK_F) {                // rare; exact check + sqrtf inside
            const float dist = fmaxf(sqrtf(r2), 1e-6f);
            const float viol = DANGER_F - dist;
            if (viol > 0.f)
                w -= REP_F * (expf(viol / DANGER_F) - 1.0f);
        }
        const float g = w * invd;
        tx = fmaf(dx, g, tx);
        ty = fmaf(dy, g, ty);
    }
    atomicAdd(&force[b * NL + i].x, tx);
    atomicAdd(&force[b * NL + i].y, ty);
}

// ---------------- Kernel D: fmag/fmean, displacement, outputs ----------------
__global__ __launch_bounds__(512) void final_kernel(
    const float* __restrict__ positions, const float2* __restrict__ force,
    float* __restrict__ out)
{
    const int b = blockIdx.x, t = threadIdx.x;
    float tx[4], ty[4], fm[4];
    float fsum = 0.f;
    #pragma unroll
    for (int m = 0; m < 4; ++m) {
        const int i = t + 512 * m;
        const float2 v = force[b * NL + i];
        tx[m] = v.x; ty[m] = v.y;
        fm[m] = sqrtf(fmaf(v.x, v.x, v.y * v.y));
        fsum += fm[m];
    }
    #pragma unroll
    for (int m = 1; m < 64; m <<= 1) fsum += __shfl_xor(fsum, m);
    __shared__ float rs[8];
    const int lane = t & 63, wid = t >> 6;
    if (lane == 0) rs[wid] = fsum;
    __syncthreads();
    float fmean = 0.f;
    #pragma unroll
    for (int w = 0; w < 8; ++w) fmean += rs[w];
    fmean *= (1.0f / NL);

    float* newpos = out;
    float* disp   = out + 2 * NB * NL;
    #pragma unroll
    for (int m = 0; m < 4; ++m) {
        const int i = t + 512 * m;
        const float fmag = fm[m];
        const float frel = fmag / (fmean + 1e-8f);
        const float dmag = fminf(fmaxf(frel * MAXD_F, MIND_F), MAXD_F);
        const float fdx = tx[m] / (fmag + 1e-8f);
        const float fdy = ty[m] / (fmag + 1e-8f);
        const float dpx = fdx * dmag, dpy = fdy * dmag;
        const float2 pi = ((const float2*)positions)[b * NL + i];
        ((float2*)newpos)[b * NL + i] = make_float2(pi.x + dpx, pi.y + dpy);
        ((float2*)disp)[b * NL + i]   = make_float2(dpx, dpy);
    }
}

extern "C" void kernel_launch(void* const* d_in, const int* in_sizes, int n_in,
                              void* d_out, int out_size, void* d_ws, size_t ws_size,
                              hipStream_t stream)
{
    const float* latents   = (const float*)d_in[0];
    const float* positions = (const float*)d_in[1];
    const float* pe_w1 = (const float*)d_in[2];
    const float* pe_b1 = (const float*)d_in[3];
    const float* pe_w2 = (const float*)d_in[4];
    const float* pe_b2 = (const float*)d_in[5];
    const float* em_w1 = (const float*)d_in[6];
    const float* em_b1 = (const float*)d_in[7];
    const float* ln_g  = (const float*)d_in[8];
    const float* ln_b  = (const float*)d_in[9];
    const float* em_w2 = (const float*)d_in[10];
    const float* em_b2 = (const float*)d_in[11];
    const float* em_w3 = (const float*)d_in[12];
    const float* em_b3 = (const float*)d_in[13];

    float* out = (float*)d_out;
    float* errors = out + 2 * 2 * NB * NL;        // third output section [B,L]

    // workspace: mnden (4 float2) then force (NB*NL float2) -- 64.1 KB total
    float2* mnden = (float2*)d_ws;
    float2* force = mnden + NB;

    mlp_kernel<<<NB * NL / PPB, 512, 0, stream>>>(
        latents, positions, pe_w1, pe_b1, pe_w2, pe_b2,
        em_w1, em_b1, ln_g, ln_b, em_w2, em_b2, em_w3, em_b3, errors);

    minmax_kernel<<<NB, 256, 0, stream>>>(errors, mnden, force);

    pair_kernel<<<NB * 8 * 32, 256, 0, stream>>>(positions, errors, mnden, force);

    final_kernel<<<NB, 512, 0, stream>>>(positions, force, out);
}

// Round 9
// 157.225 us; speedup vs baseline: 1.4443x; 1.0377x over previous
//
#include <hip/hip_runtime.h>
#include <math.h>

#define NB 4
#define NL 2048
#define ND 256
#define PPB 32   // points per block in the MLP kernel (8 waves x 4 points)

__device__ __forceinline__ float gelu_exact(float x) {
    return 0.5f * x * (1.0f + erff(x * 0.70710678118654752f));
}

// constants evaluated in double at compile time, truncated to float (XLA semantics)
#define DANGER_F ((float)(103.0 / 45.0 / 4.0))
#define DANGER2_SLACK_F ((float)(103.0 / 45.0 / 4.0 * 103.0 / 45.0 / 4.0 * 1.0001))
#define REP_F 0.3f
#define MAXD_F 5.0f
#define MIND_F 0.5f
#define OFF_F 0.1f

// ---------------- Kernel A: fused ErrorPredictor MLP ----------------
// 512 threads, 32 points per block (grid = 256 = 1 block/CU).
// Weights are staged K-tile by K-tile into double-buffered LDS (weights hit
// global exactly ONCE per block; all 8 waves re-read from LDS). Wave w owns
// points {4w..4w+3}; lane l owns 4 output channels. One barrier per tile.
// Also zeroes the force accumulator for kernel C.
__global__ __launch_bounds__(512) void mlp_kernel(
    const float* __restrict__ latents, const float* __restrict__ positions,
    const float* __restrict__ pe_w1, const float* __restrict__ pe_b1,
    const float* __restrict__ pe_w2, const float* __restrict__ pe_b2,
    const float* __restrict__ em_w1, const float* __restrict__ em_b1,
    const float* __restrict__ ln_g, const float* __restrict__ ln_b,
    const float* __restrict__ em_w2, const float* __restrict__ em_b2,
    const float* __restrict__ em_w3, const float* __restrict__ em_b3,
    float* __restrict__ errors_out, float2* __restrict__ force)
{
    const int t  = threadIdx.x;
    const int g0 = blockIdx.x * PPB;
    const int l  = t & 63;
    const int p0 = (t >> 6) * 4;     // this wave's first point (block-local)

    __shared__ float xs[PPB][320];   // concat(latents, pf); cols 0:256 reused for gelu(LN(h))
    __shared__ float pf1[PPB][68];   // pad 68: banks k,k+4,k+8,k+12 -> conflict-free
    __shared__ float posl[2 * PPB];
    __shared__ float wb[2][16 * 256]; // double-buffered weight K-tile (16KB each)

    // zero this block's slice of the force accumulator (8192 float2 / 256 blocks)
    if (t < 32) force[blockIdx.x * 32 + t] = make_float2(0.0f, 0.0f);

    // stage latents as float4 (coalesced b128): 32*64 = 2048 float4, 4/thread
    {
        const float4* src = (const float4*)(latents + (size_t)g0 * ND);
        #pragma unroll
        for (int m = 0; m < 4; ++m) {
            const int q = t + 512 * m;
            const float4 v = src[q];
            *(float4*)&xs[q >> 6][(q & 63) * 4] = v;
        }
    }
    if (t < PPB) ((float2*)posl)[t] = ((const float2*)positions)[g0 + t];
    __syncthreads();

    // position encoder layer 1: 2 -> 64, gelu. 16 lanes/point, 4 ch each.
    {
        const int p = t >> 4, j0 = t & 15;
        const float px = posl[2 * p], py = posl[2 * p + 1];
        #pragma unroll
        for (int h = 0; h < 4; ++h) {
            const int j = j0 + 16 * h;
            pf1[p][j] = gelu_exact(fmaf(px, pe_w1[j], fmaf(py, pe_w1[64 + j], pe_b1[j])));
        }
    }
    __syncthreads();
    // pe layer 2: 64 -> 64, into xs[:, 256:320]
    {
        const int p = t >> 4, j0 = t & 15;
        #pragma unroll
        for (int h = 0; h < 4; ++h) {
            const int j = j0 + 16 * h;
            float a = pe_b2[j];
            #pragma unroll 4
            for (int k = 0; k < 64; ++k)
                a = fmaf(pf1[p][k], pe_w2[k * 64 + j], a);
            xs[p][ND + j] = a;
        }
    }
    __syncthreads();

    // ---- GEMM1: h[p][c] = sum_k xs[p][k]*em_w1[k][c], K=320 in 20 tiles of 16 ----
    float acc[4][4];
    {
        const float4 b1 = *(const float4*)&em_b1[4 * l];
        #pragma unroll
        for (int p = 0; p < 4; ++p) {
            acc[p][0] = b1.x; acc[p][1] = b1.y; acc[p][2] = b1.z; acc[p][3] = b1.w;
        }
    }
    {
        const float4* __restrict__ W1v = (const float4*)em_w1;  // 20480 float4
        float4 r0 = W1v[t];            // tile 0, element t
        float4 r1 = W1v[t + 512];      // tile 0, element t+512
        for (int kt = 0; kt < 20; ++kt) {
            float* dst = wb[kt & 1];
            *(float4*)&dst[t * 4]         = r0;   // ds_write_b128, contiguous
            *(float4*)&dst[(t + 512) * 4] = r1;
            if (kt < 19) {                         // issue next tile early (hides latency)
                r0 = W1v[(kt + 1) * 1024 + t];
                r1 = W1v[(kt + 1) * 1024 + t + 512];
            }
            __syncthreads();                       // tile visible; prev-tile readers done
            const float* wcur = wb[kt & 1];
            #pragma unroll
            for (int kk = 0; kk < 16; kk += 4) {
                float xk[4][4];
                #pragma unroll
                for (int p = 0; p < 4; ++p) {
                    const float4 xq = *(const float4*)&xs[p0 + p][kt * 16 + kk];
                    xk[p][0] = xq.x; xk[p][1] = xq.y; xk[p][2] = xq.z; xk[p][3] = xq.w;
                }
                #pragma unroll
                for (int u = 0; u < 4; ++u) {
                    const float4 w = *(const float4*)&wcur[(kk + u) * 256 + 4 * l];
                    #pragma unroll
                    for (int p = 0; p < 4; ++p) {
                        acc[p][0] = fmaf(xk[p][u], w.x, acc[p][0]);
                        acc[p][1] = fmaf(xk[p][u], w.y, acc[p][1]);
                        acc[p][2] = fmaf(xk[p][u], w.z, acc[p][2]);
                        acc[p][3] = fmaf(xk[p][u], w.w, acc[p][3]);
                    }
                }
            }
            // no trailing barrier: next iter writes the OTHER buffer (dbuf)
        }
    }

    // LayerNorm: all 256 channels of each point live inside this wave
    float mu[4], rstd[4];
    #pragma unroll
    for (int p = 0; p < 4; ++p) {
        float s = acc[p][0] + acc[p][1] + acc[p][2] + acc[p][3];
        float q = acc[p][0] * acc[p][0] + acc[p][1] * acc[p][1]
                + acc[p][2] * acc[p][2] + acc[p][3] * acc[p][3];
        #pragma unroll
        for (int m = 1; m < 64; m <<= 1) {
            s += __shfl_xor(s, m);
            q += __shfl_xor(q, m);
        }
        mu[p] = s * (1.0f / 256.0f);
        rstd[p] = 1.0f / sqrtf(q * (1.0f / 256.0f) - mu[p] * mu[p] + 1e-5f);
    }
    {
        const float4 g4 = *(const float4*)&ln_g[4 * l];
        const float4 b4 = *(const float4*)&ln_b[4 * l];
        #pragma unroll
        for (int p = 0; p < 4; ++p) {
            float4 o;
            o.x = gelu_exact(fmaf((acc[p][0] - mu[p]) * rstd[p], g4.x, b4.x));
            o.y = gelu_exact(fmaf((acc[p][1] - mu[p]) * rstd[p], g4.y, b4.y));
            o.z = gelu_exact(fmaf((acc[p][2] - mu[p]) * rstd[p], g4.z, b4.z));
            o.w = gelu_exact(fmaf((acc[p][3] - mu[p]) * rstd[p], g4.w, b4.w));
            *(float4*)&xs[p0 + p][4 * l] = o;   // own rows; wave-internal ordering ok
        }
    }

    // ---- GEMM2: h2 = gelu(hs @ em_w2 + b2), K=256 in 16 tiles of 16; lane owns 2 ch ----
    float a2[4][2];
    {
        const float2 b2 = *(const float2*)&em_b2[2 * l];
        #pragma unroll
        for (int p = 0; p < 4; ++p) { a2[p][0] = b2.x; a2[p][1] = b2.y; }
    }
    {
        const float4* __restrict__ W2v = (const float4*)em_w2;  // 8192 float4
        float4 s = W2v[t];             // tile 0, element t (512 float4/tile)
        for (int kt = 0; kt < 16; ++kt) {
            float* dst = wb[kt & 1];
            *(float4*)&dst[t * 4] = s;
            if (kt < 15) s = W2v[(kt + 1) * 512 + t];
            __syncthreads();
            const float* wcur = wb[kt & 1];
            #pragma unroll
            for (int kk = 0; kk < 16; kk += 4) {
                float xk[4][4];
                #pragma unroll
                for (int p = 0; p < 4; ++p) {
                    const float4 xq = *(const float4*)&xs[p0 + p][kt * 16 + kk];
                    xk[p][0] = xq.x; xk[p][1] = xq.y; xk[p][2] = xq.z; xk[p][3] = xq.w;
                }
                #pragma unroll
                for (int u = 0; u < 4; ++u) {
                    const float2 w = *(const float2*)&wcur[(kk + u) * 128 + 2 * l];
                    #pragma unroll
                    for (int p = 0; p < 4; ++p) {
                        a2[p][0] = fmaf(xk[p][u], w.x, a2[p][0]);
                        a2[p][1] = fmaf(xk[p][u], w.y, a2[p][1]);
                    }
                }
            }
        }
    }

    // err = softplus(gelu(h2) @ em_w3 + b3), fully in-register
    {
        const float2 w3 = *(const float2*)&em_w3[2 * l];
        float r[4];
        #pragma unroll
        for (int p = 0; p < 4; ++p)
            r[p] = fmaf(gelu_exact(a2[p][0]), w3.x, gelu_exact(a2[p][1]) * w3.y);
        #pragma unroll
        for (int m = 1; m < 64; m <<= 1) {
            #pragma unroll
            for (int p = 0; p < 4; ++p) r[p] += __shfl_xor(r[p], m);
        }
        if (l == 0) {
            #pragma unroll
            for (int p = 0; p < 4; ++p) {
                const float x = r[p] + em_b3[0];
                errors_out[g0 + p0 + p] = fmaxf(x, 0.0f) + log1pf(expf(-fabsf(x)));
            }
        }
    }
}

// ---------------- Kernel C: pairwise forces + inline per-block minmax ----------------
// grid = NB * 8 * 32 (b, ic, jc); thread owns one i; 64-j chunk staged in LDS as
// float4(x, y, errn, 0). Each block recomputes the batch min/max (identical,
// deterministic across blocks). Atomic accumulate into force (zeroed by mlp).
__global__ __launch_bounds__(256) void pair_kernel(
    const float* __restrict__ positions, const float* __restrict__ errors,
    float2* __restrict__ force)
{
    const int t = threadIdx.x;
    int bid = blockIdx.x;
    const int jc = bid & 31;
    const int ic = (bid >> 5) & 7;
    const int b  = bid >> 8;
    const int i  = ic * 256 + t;

    // per-block minmax over this batch's 2048 errors (same result in every block)
    const float* e = errors + b * NL;
    float mn = 1e30f, mx = -1e30f;
    #pragma unroll
    for (int m = 0; m < 8; ++m) {
        const float v = e[t + 256 * m];
        mn = fminf(mn, v); mx = fmaxf(mx, v);
    }
    #pragma unroll
    for (int m = 1; m < 64; m <<= 1) {
        mn = fminf(mn, __shfl_xor(mn, m));
        mx = fmaxf(mx, __shfl_xor(mx, m));
    }
    __shared__ float rmn[4], rmx[4];
    const int lane = t & 63, wid = t >> 6;
    if (lane == 0) { rmn[wid] = mn; rmx[wid] = mx; }
    __syncthreads();
    mn = fminf(fminf(rmn[0], rmn[1]), fminf(rmn[2], rmn[3]));
    mx = fmaxf(fmaxf(rmx[0], rmx[1]), fmaxf(rmx[2], rmx[3]));
    const float den = (mx - mn) + 1e-8f;

    const float2 pi = ((const float2*)positions)[b * NL + i];

    __shared__ float4 pj4[64];
    if (t < 64) {
        const int j = jc * 64 + t;
        const float2 pj = ((const float2*)positions)[b * NL + j];
        pj4[t] = make_float4(pj.x, pj.y, (e[j] - mn) / den + OFF_F, 0.0f);
    }
    __syncthreads();

    // self/coincident pairs contribute exactly 0 (delta==0 -> direction 0, invd finite)
    float tx = 0.f, ty = 0.f;
    #pragma unroll 4
    for (int m = 0; m < 64; ++m) {
        const float4 v = pj4[m];
        const float dx = v.x - pi.x;
        const float dy = v.y - pi.y;
        const float r2 = fmaf(dx, dx, dy * dy);
        const bool tiny = (r2 < 1e-12f);           // ref: dist = max(sqrt(r2), 1e-6)
        const float invd = tiny ? 1e6f : rsqrtf(r2);
        float w = v.z * invd * invd;               // errn_j / dist^2
        if (r2 < DANGER2_SLACK_F) {                // rare; exact check + sqrtf inside
            const float dist = fmaxf(sqrtf(r2), 1e-6f);
            const float viol = DANGER_F - dist;
            if (viol > 0.f)
                w -= REP_F * (expf(viol / DANGER_F) - 1.0f);
        }
        const float g = w * invd;
        tx = fmaf(dx, g, tx);
        ty = fmaf(dy, g, ty);
    }
    atomicAdd(&force[b * NL + i].x, tx);
    atomicAdd(&force[b * NL + i].y, ty);
}

// ---------------- Kernel D: fmag/fmean, displacement, outputs ----------------
__global__ __launch_bounds__(512) void final_kernel(
    const float* __restrict__ positions, const float2* __restrict__ force,
    float* __restrict__ out)
{
    const int b = blockIdx.x, t = threadIdx.x;
    float tx[4], ty[4], fm[4];
    float fsum = 0.f;
    #pragma unroll
    for (int m = 0; m < 4; ++m) {
        const int i = t + 512 * m;
        const float2 v = force[b * NL + i];
        tx[m] = v.x; ty[m] = v.y;
        fm[m] = sqrtf(fmaf(v.x, v.x, v.y * v.y));
        fsum += fm[m];
    }
    #pragma unroll
    for (int m = 1; m < 64; m <<= 1) fsum += __shfl_xor(fsum, m);
    __shared__ float rs[8];
    const int lane = t & 63, wid = t >> 6;
    if (lane == 0) rs[wid] = fsum;
    __syncthreads();
    float fmean = 0.f;
    #pragma unroll
    for (int w = 0; w < 8; ++w) fmean += rs[w];
    fmean *= (1.0f / NL);

    float* newpos = out;
    float* disp   = out + 2 * NB * NL;
    #pragma unroll
    for (int m = 0; m < 4; ++m) {
        const int i = t + 512 * m;
        const float fmag = fm[m];
        const float frel = fmag / (fmean + 1e-8f);
        const float dmag = fminf(fmaxf(frel * MAXD_F, MIND_F), MAXD_F);
        const float fdx = tx[m] / (fmag + 1e-8f);
        const float fdy = ty[m] / (fmag + 1e-8f);
        const float dpx = fdx * dmag, dpy = fdy * dmag;
        const float2 pi = ((const float2*)positions)[b * NL + i];
        ((float2*)newpos)[b * NL + i] = make_float2(pi.x + dpx, pi.y + dpy);
        ((float2*)disp)[b * NL + i]   = make_float2(dpx, dpy);
    }
}

extern "C" void kernel_launch(void* const* d_in, const int* in_sizes, int n_in,
                              void* d_out, int out_size, void* d_ws, size_t ws_size,
                              hipStream_t stream)
{
    const float* latents   = (const float*)d_in[0];
    const float* positions = (const float*)d_in[1];
    const float* pe_w1 = (const float*)d_in[2];
    const float* pe_b1 = (const float*)d_in[3];
    const float* pe_w2 = (const float*)d_in[4];
    const float* pe_b2 = (const float*)d_in[5];
    const float* em_w1 = (const float*)d_in[6];
    const float* em_b1 = (const float*)d_in[7];
    const float* ln_g  = (const float*)d_in[8];
    const float* ln_b  = (const float*)d_in[9];
    const float* em_w2 = (const float*)d_in[10];
    const float* em_b2 = (const float*)d_in[11];
    const float* em_w3 = (const float*)d_in[12];
    const float* em_b3 = (const float*)d_in[13];

    float* out = (float*)d_out;
    float* errors = out + 2 * 2 * NB * NL;        // third output section [B,L]

    float2* force = (float2*)d_ws;                // NB*NL float2 = 64 KB

    mlp_kernel<<<NB * NL / PPB, 512, 0, stream>>>(
        latents, positions, pe_w1, pe_b1, pe_w2, pe_b2,
        em_w1, em_b1, ln_g, ln_b, em_w2, em_b2, em_w3, em_b3, errors, force);

    pair_kernel<<<NB * 8 * 32, 256, 0, stream>>>(positions, errors, force);

    final_kernel<<<NB, 512, 0, stream>>>(positions, force, out);
}